// Round 1
// baseline (3090.744 us; speedup 1.0000x reference)
//
#include <hip/hip_runtime.h>

// ---------------------------------------------------------------------------
// GINEConv GNN forward on MI355X.
// Phases:
//   1. prep: fold BN(g,b,beta,bias) into per-channel scale/offset vectors
//   2. CSR build by dst (count -> scan -> scatter)  [reused by all 4 layers]
//   3. input encoder GEMM (x @ in_W, BN+ReLU epilogue)
//   4. per layer: agg_kernel (edge MLP + gather h[src] + sum into dst,
//      epilogue t=(1+eps)h+agg), conv GEMM (t @ W, BN+ReLU+residual epilogue)
//   5. pool (atomicAdd per graph), output MLP (2 GEMMs)
// ---------------------------------------------------------------------------

__global__ __launch_bounds__(256) void prep_kernel(
    const float* __restrict__ in_b, const float* __restrict__ in_g, const float* __restrict__ in_beta,
    const float* __restrict__ edge_b, const float* __restrict__ edge_g, const float* __restrict__ edge_beta,
    const float* __restrict__ bn_g, const float* __restrict__ bn_b,
    const float* __restrict__ out_b1, const float* __restrict__ out_g1, const float* __restrict__ out_beta1,
    float* __restrict__ consts)
{
    int c = threadIdx.x;
    if (c >= 128) return;
    const float rs = rsqrtf(1.0f + 1e-5f);
    float es = in_g[c] * rs;
    consts[c]       = es;                          // enc scale
    consts[128 + c] = in_b[c] * es + in_beta[c];   // enc offset
    for (int l = 0; l < 4; ++l) {
        float s = edge_g[l*128 + c] * rs;
        consts[256  + l*128 + c] = s;                                     // edge scale
        consts[768  + l*128 + c] = edge_b[l*128 + c] * s + edge_beta[l*128 + c]; // edge off
        float bs = bn_g[l*128 + c] * rs;
        consts[1280 + l*128 + c] = bs;             // conv bn scale (conv has no bias)
        consts[1792 + l*128 + c] = bn_b[l*128 + c];// conv bn offset = beta
    }
    float s1 = out_g1[c] * rs;
    consts[2304 + c] = s1;
    consts[2432 + c] = out_b1[c] * s1 + out_beta1[c];
}

__global__ __launch_bounds__(256) void count_kernel(
    const int* __restrict__ dst, int E, int* __restrict__ cnt)
{
    for (int e = blockIdx.x*blockDim.x + threadIdx.x; e < E; e += gridDim.x*blockDim.x)
        atomicAdd(&cnt[dst[e]], 1);
}

__global__ __launch_bounds__(1024) void scan_kernel(
    const int* __restrict__ cnt, int n, int E,
    int* __restrict__ offs, int* __restrict__ cursor)
{
    __shared__ int sh[1024];
    const int t = threadIdx.x;
    const int chunk = (n + 1023) >> 10;
    const int lo = t * chunk;
    const int hi = min(n, lo + chunk);
    int s = 0;
    for (int i = lo; i < hi; ++i) s += cnt[i];
    sh[t] = s;
    __syncthreads();
    for (int d = 1; d < 1024; d <<= 1) {
        int v = (t >= d) ? sh[t - d] : 0;
        __syncthreads();
        sh[t] += v;
        __syncthreads();
    }
    int base = sh[t] - s;   // exclusive prefix of this chunk
    for (int i = lo; i < hi; ++i) { int c = cnt[i]; offs[i] = base; cursor[i] = base; base += c; }
    if (t == 1023) offs[n] = E;
}

__global__ __launch_bounds__(256) void scatter_kernel(
    const int* __restrict__ dst, int E, int* __restrict__ cursor, int* __restrict__ perm)
{
    for (int e = blockIdx.x*blockDim.x + threadIdx.x; e < E; e += gridDim.x*blockDim.x) {
        int p = atomicAdd(&cursor[dst[e]], 1);
        perm[p] = e;
    }
}

// out[r][c] = relu?( (in[r]@W)[c]*scale[c] + off[c] ) (+ resid[r][c])
// One wave per row; lane computes channels (2*lane, 2*lane+1); W staged in LDS.
// NOTE: resid/out may alias (same row read-then-write by same thread) -> no restrict.
__global__ __launch_bounds__(256) void gemm128_kernel(
    const float* __restrict__ in, int rows,
    const float* __restrict__ W,
    const float* __restrict__ scale, const float* __restrict__ off,
    const float* resid, float* out, int do_relu)
{
    __shared__ float Ws[128*128];
    for (int i = threadIdx.x*4; i < 128*128; i += 256*4)
        *(float4*)&Ws[i] = *(const float4*)&W[i];
    __syncthreads();
    const int wave = threadIdx.x >> 6, lane = threadIdx.x & 63;
    const int c0 = lane * 2;
    const float sc0 = scale ? scale[c0]   : 1.0f;
    const float sc1 = scale ? scale[c0+1] : 1.0f;
    const float of0 = off ? off[c0]   : 0.0f;
    const float of1 = off ? off[c0+1] : 0.0f;
    for (int row = blockIdx.x*4 + wave; row < rows; row += gridDim.x*4) {
        const float2 xv = *(const float2*)&in[row*128 + c0];
        float acc0 = 0.f, acc1 = 0.f;
        #pragma unroll
        for (int k = 0; k < 128; ++k) {
            float xk = __shfl((k & 1) ? xv.y : xv.x, k >> 1, 64);
            float2 w = *(const float2*)&Ws[k*128 + c0];
            acc0 = fmaf(xk, w.x, acc0);
            acc1 = fmaf(xk, w.y, acc1);
        }
        float y0 = fmaf(acc0, sc0, of0);
        float y1 = fmaf(acc1, sc1, of1);
        if (do_relu) { y0 = fmaxf(y0, 0.f); y1 = fmaxf(y1, 0.f); }
        if (resid) {
            const float2 r = *(const float2*)&resid[row*128 + c0];
            y0 += r.x; y1 += r.y;
        }
        *(float2*)&out[row*128 + c0] = make_float2(y0, y1);
    }
}

// One wave per dst node. For each incoming edge: ea = relu(bn(attr@Wl)),
// m = relu(h[src]+ea), accumulate. Epilogue: outT = (1+eps)*h[node] + acc.
__global__ __launch_bounds__(256) void agg_kernel(
    const float* __restrict__ h, const float* __restrict__ attr,
    const int* __restrict__ src, const int* __restrict__ perm,
    const int* __restrict__ offs, const float* __restrict__ Wl,
    const float* __restrict__ escale, const float* __restrict__ eoff,
    const float* __restrict__ epsp, int layer,
    float* __restrict__ outT, int n)
{
    __shared__ float Ws[16*128];
    for (int i = threadIdx.x*4; i < 16*128; i += 256*4)
        *(float4*)&Ws[i] = *(const float4*)&Wl[i];
    __syncthreads();
    const int wave = threadIdx.x >> 6, lane = threadIdx.x & 63;
    const int c0 = lane * 2;
    const float sc0 = escale[c0], sc1 = escale[c0+1];
    const float of0 = eoff[c0],   of1 = eoff[c0+1];
    const float epsv = 1.0f + epsp[layer];
    for (int node = blockIdx.x*4 + wave; node < n; node += gridDim.x*4) {
        float acc0 = 0.f, acc1 = 0.f;
        const int beg = offs[node], end = offs[node+1];
        for (int i = beg; i < end; ++i) {
            const int e = perm[i];
            const int s = src[e];
            const float4* ap = (const float4*)(attr + e*16);
            float av[16];
            *(float4*)&av[0]  = ap[0];
            *(float4*)&av[4]  = ap[1];
            *(float4*)&av[8]  = ap[2];
            *(float4*)&av[12] = ap[3];
            float r0 = 0.f, r1 = 0.f;
            #pragma unroll
            for (int k = 0; k < 16; ++k) {
                float2 w = *(const float2*)&Ws[k*128 + c0];
                r0 = fmaf(av[k], w.x, r0);
                r1 = fmaf(av[k], w.y, r1);
            }
            float ea0 = fmaxf(fmaf(r0, sc0, of0), 0.f);
            float ea1 = fmaxf(fmaf(r1, sc1, of1), 0.f);
            const float2 hv = *(const float2*)&h[s*128 + c0];
            acc0 += fmaxf(hv.x + ea0, 0.f);
            acc1 += fmaxf(hv.y + ea1, 0.f);
        }
        const float2 hn = *(const float2*)&h[node*128 + c0];
        *(float2*)&outT[node*128 + c0] =
            make_float2(fmaf(epsv, hn.x, acc0), fmaf(epsv, hn.y, acc1));
    }
}

__global__ __launch_bounds__(256) void pool_kernel(
    const float* __restrict__ h, const int* __restrict__ batch,
    float* __restrict__ pooled, int n)
{
    for (int idx = blockIdx.x*blockDim.x + threadIdx.x; idx < n*128;
         idx += gridDim.x*blockDim.x) {
        int node = idx >> 7, c = idx & 127;
        atomicAdd(&pooled[batch[node]*128 + c], h[idx]);
    }
}

extern "C" void kernel_launch(void* const* d_in, const int* in_sizes, int n_in,
                              void* d_out, int out_size, void* d_ws, size_t ws_size,
                              hipStream_t stream)
{
    const float* x         = (const float*)d_in[0];
    const int*   eidx      = (const int*)d_in[1];
    const float* eattr     = (const float*)d_in[2];
    const int*   batch     = (const int*)d_in[3];
    const float* in_W      = (const float*)d_in[4];
    const float* in_b      = (const float*)d_in[5];
    const float* in_g      = (const float*)d_in[6];
    const float* in_beta   = (const float*)d_in[7];
    const float* edge_W    = (const float*)d_in[8];
    const float* edge_b    = (const float*)d_in[9];
    const float* edge_g    = (const float*)d_in[10];
    const float* edge_beta = (const float*)d_in[11];
    const float* conv_W    = (const float*)d_in[12];
    const float* epsp      = (const float*)d_in[13];
    const float* bn_g      = (const float*)d_in[14];
    const float* bn_b      = (const float*)d_in[15];
    const float* out_W1    = (const float*)d_in[16];
    const float* out_b1    = (const float*)d_in[17];
    const float* out_g1    = (const float*)d_in[18];
    const float* out_beta1 = (const float*)d_in[19];
    const float* out_W2    = (const float*)d_in[20];
    const float* out_b2    = (const float*)d_in[21];

    const int N = in_sizes[0] / 128;
    const int E = in_sizes[1] / 2;
    const int* src = eidx;
    const int* dst = eidx + E;

    char* ws = (char*)d_ws;
    size_t o = 0;
    float* A      = (float*)(ws + o); o += (size_t)N * 128 * 4;   // h (and prev)
    float* C      = (float*)(ws + o); o += (size_t)N * 128 * 4;   // t = (1+eps)h+agg
    int*   perm   = (int*)(ws + o);   o += (size_t)E * 4;
    int*   offs   = (int*)(ws + o);   o += (size_t)(N + 1) * 4;
    o = (o + 255) & ~(size_t)255;
    int*   cursor = (int*)(ws + o);   o += (size_t)N * 4;
    o = (o + 255) & ~(size_t)255;
    int*   cnt    = (int*)(ws + o);   o += (size_t)N * 4;
    o = (o + 255) & ~(size_t)255;
    float* pooled = (float*)(ws + o); o += 512 * 128 * 4;
    float* o1     = (float*)(ws + o); o += 512 * 128 * 4;
    float* consts = (float*)(ws + o); o += 2560 * 4;

    prep_kernel<<<1, 256, 0, stream>>>(in_b, in_g, in_beta, edge_b, edge_g, edge_beta,
                                       bn_g, bn_b, out_b1, out_g1, out_beta1, consts);

    hipMemsetAsync(cnt, 0, (size_t)N * 4, stream);
    count_kernel<<<2048, 256, 0, stream>>>(dst, E, cnt);
    scan_kernel<<<1, 1024, 0, stream>>>(cnt, N, E, offs, cursor);
    scatter_kernel<<<2048, 256, 0, stream>>>(dst, E, cursor, perm);

    // input encoder
    gemm128_kernel<<<1024, 256, 0, stream>>>(x, N, in_W, consts, consts + 128,
                                             nullptr, A, 1);

    for (int l = 0; l < 4; ++l) {
        agg_kernel<<<2048, 256, 0, stream>>>(A, eattr, src, perm, offs,
                                             edge_W + l*16*128,
                                             consts + 256 + l*128,
                                             consts + 768 + l*128,
                                             epsp, l, C, N);
        gemm128_kernel<<<1024, 256, 0, stream>>>(C, N, conv_W + l*128*128,
                                                 consts + 1280 + l*128,
                                                 consts + 1792 + l*128,
                                                 A, A, 1);
    }

    hipMemsetAsync(pooled, 0, 512 * 128 * 4, stream);
    pool_kernel<<<2048, 256, 0, stream>>>(A, batch, pooled, N);

    gemm128_kernel<<<128, 256, 0, stream>>>(pooled, 512, out_W1,
                                            consts + 2304, consts + 2432,
                                            nullptr, o1, 1);
    gemm128_kernel<<<128, 256, 0, stream>>>(o1, 512, out_W2,
                                            nullptr, out_b2, nullptr,
                                            (float*)d_out, 0);
}

// Round 2
// 2162.260 us; speedup vs baseline: 1.4294x; 1.4294x over previous
//
#include <hip/hip_runtime.h>

#define NGRAPH 512

// ---------------------------------------------------------------------------
// GINEConv GNN forward on MI355X.  R2: latency-focused agg rewrite.
//  - edge descriptors (src*128, e*16) prebuilt at scatter -> no index chain
//  - agg: edge-MLP W held in VGPRs, edge loop unrolled x4, loads batched
//  - pool: segment reduction over sorted batch (no atomics)
//  - gemm128: scalar (SGPR) x-row loads, 2 rows/wave, no per-k shuffle
// ---------------------------------------------------------------------------

__global__ __launch_bounds__(256) void prep_kernel(
    const float* __restrict__ in_b, const float* __restrict__ in_g, const float* __restrict__ in_beta,
    const float* __restrict__ edge_b, const float* __restrict__ edge_g, const float* __restrict__ edge_beta,
    const float* __restrict__ bn_g, const float* __restrict__ bn_b,
    const float* __restrict__ out_b1, const float* __restrict__ out_g1, const float* __restrict__ out_beta1,
    float* __restrict__ consts)
{
    int c = threadIdx.x;
    if (c >= 128) return;
    const float rs = rsqrtf(1.0f + 1e-5f);
    float es = in_g[c] * rs;
    consts[c]       = es;
    consts[128 + c] = in_b[c] * es + in_beta[c];
    for (int l = 0; l < 4; ++l) {
        float s = edge_g[l*128 + c] * rs;
        consts[256  + l*128 + c] = s;
        consts[768  + l*128 + c] = edge_b[l*128 + c] * s + edge_beta[l*128 + c];
        float bs = bn_g[l*128 + c] * rs;
        consts[1280 + l*128 + c] = bs;
        consts[1792 + l*128 + c] = bn_b[l*128 + c];
    }
    float s1 = out_g1[c] * rs;
    consts[2304 + c] = s1;
    consts[2432 + c] = out_b1[c] * s1 + out_beta1[c];
}

__global__ __launch_bounds__(256) void count_kernel(
    const int* __restrict__ dst, int E, int* __restrict__ cnt)
{
    for (int e = blockIdx.x*blockDim.x + threadIdx.x; e < E; e += gridDim.x*blockDim.x)
        atomicAdd(&cnt[dst[e]], 1);
}

__global__ __launch_bounds__(1024) void scan_kernel(
    const int* __restrict__ cnt, int n, int E,
    int* __restrict__ offs, int* __restrict__ cursor)
{
    __shared__ int sh[1024];
    const int t = threadIdx.x;
    const int chunk = (n + 1023) >> 10;
    const int lo = t * chunk;
    const int hi = min(n, lo + chunk);
    int s = 0;
    for (int i = lo; i < hi; ++i) s += cnt[i];
    sh[t] = s;
    __syncthreads();
    for (int d = 1; d < 1024; d <<= 1) {
        int v = (t >= d) ? sh[t - d] : 0;
        __syncthreads();
        sh[t] += v;
        __syncthreads();
    }
    int base = sh[t] - s;
    for (int i = lo; i < hi; ++i) { int c = cnt[i]; offs[i] = base; cursor[i] = base; base += c; }
    if (t == 1023) offs[n] = E;
}

// Builds fused edge descriptors: ed[p] = (src*128, e*16), CSR-ordered by dst.
__global__ __launch_bounds__(256) void scatter_kernel(
    const int* __restrict__ src, const int* __restrict__ dst, int E,
    int* __restrict__ cursor, int2* __restrict__ ed)
{
    for (int e = blockIdx.x*blockDim.x + threadIdx.x; e < E; e += gridDim.x*blockDim.x) {
        int p = atomicAdd(&cursor[dst[e]], 1);
        ed[p] = make_int2(src[e] * 128, e * 16);
    }
}

// goff[g] = first node index with batch[node] >= g (batch is sorted)
__global__ __launch_bounds__(256) void goff_kernel(
    const int* __restrict__ batch, int n, int* __restrict__ goff)
{
    int g = blockIdx.x*blockDim.x + threadIdx.x;
    if (g > NGRAPH) return;
    if (g == NGRAPH) { goff[NGRAPH] = n; return; }
    int lo = 0, hi = n;
    while (lo < hi) { int m = (lo + hi) >> 1; if (batch[m] < g) lo = m + 1; else hi = m; }
    goff[g] = lo;
}

// out[r] = relu?((in[r]@W)*scale+off) (+resid[r]); 2 rows/wave, W in LDS,
// x-row read through a wave-uniform scalar pointer (SGPR operand FMAs).
__global__ __launch_bounds__(256) void gemm128_kernel(
    const float* __restrict__ in, int rows,
    const float* __restrict__ W,
    const float* __restrict__ scale, const float* __restrict__ off,
    const float* resid, float* out, int do_relu)
{
    __shared__ float Ws[128*128];
    for (int i = threadIdx.x*4; i < 128*128; i += 256*4)
        *(float4*)&Ws[i] = *(const float4*)&W[i];
    __syncthreads();
    const int wave = threadIdx.x >> 6, lane = threadIdx.x & 63;
    const int c0 = lane * 2;
    const float sc0 = scale ? scale[c0]   : 1.0f;
    const float sc1 = scale ? scale[c0+1] : 1.0f;
    const float of0 = off ? off[c0]   : 0.0f;
    const float of1 = off ? off[c0+1] : 0.0f;
    for (int rp = blockIdx.x*4 + wave; rp*2 < rows; rp += gridDim.x*4) {
        const int row0 = __builtin_amdgcn_readfirstlane(rp * 2);
        const float* xr = in + (size_t)row0 * 128;
        float a00 = 0.f, a01 = 0.f, a10 = 0.f, a11 = 0.f;
        #pragma unroll 8
        for (int k = 0; k < 128; ++k) {
            float x0 = xr[k];
            float x1 = xr[128 + k];
            float2 w = *(const float2*)&Ws[k*128 + c0];
            a00 = fmaf(x0, w.x, a00); a01 = fmaf(x0, w.y, a01);
            a10 = fmaf(x1, w.x, a10); a11 = fmaf(x1, w.y, a11);
        }
        float y00 = fmaf(a00, sc0, of0), y01 = fmaf(a01, sc1, of1);
        float y10 = fmaf(a10, sc0, of0), y11 = fmaf(a11, sc1, of1);
        if (do_relu) {
            y00 = fmaxf(y00, 0.f); y01 = fmaxf(y01, 0.f);
            y10 = fmaxf(y10, 0.f); y11 = fmaxf(y11, 0.f);
        }
        if (resid) {
            float2 r0 = *(const float2*)&resid[(size_t)row0*128 + c0];
            float2 r1 = *(const float2*)&resid[(size_t)(row0+1)*128 + c0];
            y00 += r0.x; y01 += r0.y; y10 += r1.x; y11 += r1.y;
        }
        *(float2*)&out[(size_t)row0*128 + c0]     = make_float2(y00, y01);
        *(float2*)&out[(size_t)(row0+1)*128 + c0] = make_float2(y10, y11);
    }
}

__device__ __forceinline__ void acc_edge(
    const float4* a, const float2* wv,
    float sc0, float sc1, float of0, float of1,
    float2 hv, float& acc0, float& acc1)
{
    const float* av = (const float*)a;
    float r0 = 0.f, r1 = 0.f;
    #pragma unroll
    for (int k = 0; k < 16; ++k) {
        r0 = fmaf(av[k], wv[k].x, r0);
        r1 = fmaf(av[k], wv[k].y, r1);
    }
    float ea0 = fmaxf(fmaf(r0, sc0, of0), 0.f);
    float ea1 = fmaxf(fmaf(r1, sc1, of1), 0.f);
    acc0 += fmaxf(hv.x + ea0, 0.f);
    acc1 += fmaxf(hv.y + ea1, 0.f);
}

// One wave per dst node; edge-MLP weights in VGPRs; edge loop unrolled x4.
__global__ __launch_bounds__(256) void agg_kernel(
    const float* __restrict__ h, const float* __restrict__ attr,
    const int2* __restrict__ ed, const int* __restrict__ offs,
    const float* __restrict__ Wl,
    const float* __restrict__ escale, const float* __restrict__ eoff,
    const float* __restrict__ epsp, int layer,
    float* __restrict__ outT, int n)
{
    const int wave = threadIdx.x >> 6, lane = threadIdx.x & 63;
    const int c0 = lane * 2;
    float2 wv[16];
    #pragma unroll
    for (int k = 0; k < 16; ++k) wv[k] = *(const float2*)&Wl[k*128 + c0];
    const float sc0 = escale[c0], sc1 = escale[c0+1];
    const float of0 = eoff[c0],   of1 = eoff[c0+1];
    const float epsv = 1.0f + epsp[layer];
    for (int node = blockIdx.x*4 + wave; node < n; node += gridDim.x*4) {
        float acc0 = 0.f, acc1 = 0.f;
        const int beg = offs[node], end = offs[node+1];
        int i = beg;
        const int n4 = beg + ((end - beg) & ~3);
        for (; i < n4; i += 4) {
            const int2 d0 = ed[i], d1 = ed[i+1], d2 = ed[i+2], d3 = ed[i+3];
            const float2 h0 = *(const float2*)&h[d0.x + c0];
            const float2 h1 = *(const float2*)&h[d1.x + c0];
            const float2 h2 = *(const float2*)&h[d2.x + c0];
            const float2 h3 = *(const float2*)&h[d3.x + c0];
            float4 a0[4], a1[4], a2[4], a3[4];
            #pragma unroll
            for (int q = 0; q < 4; ++q) {
                a0[q] = ((const float4*)(attr + d0.y))[q];
                a1[q] = ((const float4*)(attr + d1.y))[q];
                a2[q] = ((const float4*)(attr + d2.y))[q];
                a3[q] = ((const float4*)(attr + d3.y))[q];
            }
            acc_edge(a0, wv, sc0, sc1, of0, of1, h0, acc0, acc1);
            acc_edge(a1, wv, sc0, sc1, of0, of1, h1, acc0, acc1);
            acc_edge(a2, wv, sc0, sc1, of0, of1, h2, acc0, acc1);
            acc_edge(a3, wv, sc0, sc1, of0, of1, h3, acc0, acc1);
        }
        for (; i < end; ++i) {
            const int2 d = ed[i];
            const float2 hv = *(const float2*)&h[d.x + c0];
            float4 a[4];
            #pragma unroll
            for (int q = 0; q < 4; ++q) a[q] = ((const float4*)(attr + d.y))[q];
            acc_edge(a, wv, sc0, sc1, of0, of1, hv, acc0, acc1);
        }
        const float2 hn = *(const float2*)&h[node*128 + c0];
        *(float2*)&outT[node*128 + c0] =
            make_float2(fmaf(epsv, hn.x, acc0), fmaf(epsv, hn.y, acc1));
    }
}

// Segment-sum pooling over sorted batch: one wave per graph.
__global__ __launch_bounds__(256) void pool_kernel(
    const float* __restrict__ h, const int* __restrict__ goff,
    float* __restrict__ pooled)
{
    const int wave = threadIdx.x >> 6, lane = threadIdx.x & 63;
    const int g = blockIdx.x*4 + wave;
    if (g >= NGRAPH) return;
    const int c0 = lane * 2;
    float ax = 0.f, ay = 0.f;
    const int beg = goff[g], end = goff[g+1];
    for (int node = beg; node < end; ++node) {
        float2 v = *(const float2*)&h[node*128 + c0];
        ax += v.x; ay += v.y;
    }
    *(float2*)&pooled[g*128 + c0] = make_float2(ax, ay);
}

extern "C" void kernel_launch(void* const* d_in, const int* in_sizes, int n_in,
                              void* d_out, int out_size, void* d_ws, size_t ws_size,
                              hipStream_t stream)
{
    const float* x         = (const float*)d_in[0];
    const int*   eidx      = (const int*)d_in[1];
    const float* eattr     = (const float*)d_in[2];
    const int*   batch     = (const int*)d_in[3];
    const float* in_W      = (const float*)d_in[4];
    const float* in_b      = (const float*)d_in[5];
    const float* in_g      = (const float*)d_in[6];
    const float* in_beta   = (const float*)d_in[7];
    const float* edge_W    = (const float*)d_in[8];
    const float* edge_b    = (const float*)d_in[9];
    const float* edge_g    = (const float*)d_in[10];
    const float* edge_beta = (const float*)d_in[11];
    const float* conv_W    = (const float*)d_in[12];
    const float* epsp      = (const float*)d_in[13];
    const float* bn_g      = (const float*)d_in[14];
    const float* bn_b      = (const float*)d_in[15];
    const float* out_W1    = (const float*)d_in[16];
    const float* out_b1    = (const float*)d_in[17];
    const float* out_g1    = (const float*)d_in[18];
    const float* out_beta1 = (const float*)d_in[19];
    const float* out_W2    = (const float*)d_in[20];
    const float* out_b2    = (const float*)d_in[21];

    const int N = in_sizes[0] / 128;
    const int E = in_sizes[1] / 2;
    const int* src = eidx;
    const int* dst = eidx + E;

    char* ws = (char*)d_ws;
    size_t o = 0;
    float* A      = (float*)(ws + o); o += (size_t)N * 128 * 4;
    float* C      = (float*)(ws + o); o += (size_t)N * 128 * 4;
    int2*  ed     = (int2*)(ws + o);  o += (size_t)E * 8;
    int*   offs   = (int*)(ws + o);   o += (size_t)(N + 1) * 4;
    o = (o + 255) & ~(size_t)255;
    int*   cursor = (int*)(ws + o);   o += (size_t)N * 4;
    o = (o + 255) & ~(size_t)255;
    int*   cnt    = (int*)(ws + o);   o += (size_t)N * 4;
    o = (o + 255) & ~(size_t)255;
    int*   goff   = (int*)(ws + o);   o += (NGRAPH + 1) * 4;
    o = (o + 255) & ~(size_t)255;
    float* pooled = (float*)(ws + o); o += NGRAPH * 128 * 4;
    float* o1     = (float*)(ws + o); o += NGRAPH * 128 * 4;
    float* consts = (float*)(ws + o); o += 2560 * 4;

    prep_kernel<<<1, 256, 0, stream>>>(in_b, in_g, in_beta, edge_b, edge_g, edge_beta,
                                       bn_g, bn_b, out_b1, out_g1, out_beta1, consts);

    hipMemsetAsync(cnt, 0, (size_t)N * 4, stream);
    count_kernel<<<2048, 256, 0, stream>>>(dst, E, cnt);
    scan_kernel<<<1, 1024, 0, stream>>>(cnt, N, E, offs, cursor);
    scatter_kernel<<<2048, 256, 0, stream>>>(src, dst, E, cursor, ed);
    goff_kernel<<<3, 256, 0, stream>>>(batch, N, goff);

    gemm128_kernel<<<2048, 256, 0, stream>>>(x, N, in_W, consts, consts + 128,
                                             nullptr, A, 1);

    for (int l = 0; l < 4; ++l) {
        agg_kernel<<<2048, 256, 0, stream>>>(A, eattr, ed, offs,
                                             edge_W + l*16*128,
                                             consts + 256 + l*128,
                                             consts + 768 + l*128,
                                             epsp, l, C, N);
        gemm128_kernel<<<2048, 256, 0, stream>>>(C, N, conv_W + l*128*128,
                                                 consts + 1280 + l*128,
                                                 consts + 1792 + l*128,
                                                 A, A, 1);
    }

    pool_kernel<<<128, 256, 0, stream>>>(A, goff, pooled);

    gemm128_kernel<<<16, 256, 0, stream>>>(pooled, NGRAPH, out_W1,
                                           consts + 2304, consts + 2432,
                                           nullptr, o1, 1);
    gemm128_kernel<<<16, 256, 0, stream>>>(o1, NGRAPH, out_W2,
                                           nullptr, out_b2, nullptr,
                                           (float*)d_out, 0);
}

// Round 3
// 998.198 us; speedup vs baseline: 3.0963x; 2.1662x over previous
//
#include <hip/hip_runtime.h>
#include <stdint.h>

typedef uint32_t u32;
typedef _Float16 h2 __attribute__((ext_vector_type(2)));
typedef __attribute__((ext_vector_type(8))) short bf16x8;
typedef __attribute__((ext_vector_type(4))) float f32x4;

#define NGRAPH 512

__device__ __forceinline__ float uif(u32 u) { return __builtin_bit_cast(float, u); }
__device__ __forceinline__ u32 fiu(float f) { return __builtin_bit_cast(u32, f); }
__device__ __forceinline__ unsigned short bf16r(float f) {
    return (unsigned short)((fiu(f) + 0x8000u) >> 16);
}
__device__ __forceinline__ u32 pack_bf16(float lo, float hi) {
    return ((fiu(lo) + 0x8000u) >> 16) | ((fiu(hi) + 0x8000u) & 0xFFFF0000u);
}
__device__ __forceinline__ u32 pkh(float a, float b) {
    unsigned short la = __builtin_bit_cast(unsigned short, (_Float16)a);
    unsigned short hb = __builtin_bit_cast(unsigned short, (_Float16)b);
    return (u32)la | ((u32)hb << 16);
}
__device__ __forceinline__ float fdot2w(u32 a, u32 b, float c) {
#if __has_builtin(__builtin_amdgcn_fdot2)
    return __builtin_amdgcn_fdot2(__builtin_bit_cast(h2, a),
                                  __builtin_bit_cast(h2, b), c, false);
#else
    h2 av = __builtin_bit_cast(h2, a), bv = __builtin_bit_cast(h2, b);
    return c + (float)av[0]*(float)bv[0] + (float)av[1]*(float)bv[1];
#endif
}

// ---------------------------------------------------------------------------
// prep: BN folding + f16-packed edge-MLP weight pairs
// consts: [0]enc_s [128]enc_o [256+l*128]edge_s [768+l*128]edge_o
//         [1280+l*128]conv_s [1792+l*128]conv_o [2304]out1_s [2432]out1_o
// wpk[(l*8+kk)*128+c] = half2(W[2kk][c], W[2kk+1][c])
// ---------------------------------------------------------------------------
__global__ __launch_bounds__(256) void prep_kernel(
    const float* __restrict__ in_b, const float* __restrict__ in_g, const float* __restrict__ in_beta,
    const float* __restrict__ edge_W,
    const float* __restrict__ edge_b, const float* __restrict__ edge_g, const float* __restrict__ edge_beta,
    const float* __restrict__ bn_g, const float* __restrict__ bn_b,
    const float* __restrict__ out_b1, const float* __restrict__ out_g1, const float* __restrict__ out_beta1,
    float* __restrict__ consts, u32* __restrict__ wpk)
{
    int c = threadIdx.x;
    if (c >= 128) return;
    const float rs = rsqrtf(1.0f + 1e-5f);
    float es = in_g[c] * rs;
    consts[c]       = es;
    consts[128 + c] = in_b[c] * es + in_beta[c];
    for (int l = 0; l < 4; ++l) {
        float s = edge_g[l*128 + c] * rs;
        consts[256  + l*128 + c] = s;
        consts[768  + l*128 + c] = edge_b[l*128 + c] * s + edge_beta[l*128 + c];
        float bs = bn_g[l*128 + c] * rs;
        consts[1280 + l*128 + c] = bs;
        consts[1792 + l*128 + c] = bn_b[l*128 + c];
        for (int kk = 0; kk < 8; ++kk) {
            float w0 = edge_W[(l*16 + 2*kk)*128 + c];
            float w1 = edge_W[(l*16 + 2*kk + 1)*128 + c];
            wpk[(l*8 + kk)*128 + c] = pkh(w0, w1);
        }
    }
    float s1 = out_g1[c] * rs;
    consts[2304 + c] = s1;
    consts[2432 + c] = out_b1[c] * s1 + out_beta1[c];
}

// Wt[w][n][k] = bf16(W[w][k][n]); w=0 encoder, w=1..4 conv layers
__global__ __launch_bounds__(256) void prepw_kernel(
    const float* __restrict__ in_W, const float* __restrict__ conv_W,
    unsigned short* __restrict__ WtAll)
{
    for (int idx = blockIdx.x*blockDim.x + threadIdx.x; idx < 5*128*128;
         idx += gridDim.x*blockDim.x) {
        int w = idx >> 14, rem = idx & 16383;
        int nn = rem >> 7, kk = rem & 127;
        const float* S = (w == 0) ? in_W : conv_W + (size_t)(w-1)*16384;
        WtAll[idx] = bf16r(S[kk*128 + nn]);
    }
}

__global__ __launch_bounds__(256) void xconv_kernel(
    const float* __restrict__ x, unsigned short* __restrict__ x16, int n4)
{
    for (int i = blockIdx.x*blockDim.x + threadIdx.x; i < n4;
         i += gridDim.x*blockDim.x) {
        float4 v = *(const float4*)(x + (size_t)i*4);
        ushort4 o;
        o.x = bf16r(v.x); o.y = bf16r(v.y); o.z = bf16r(v.z); o.w = bf16r(v.w);
        *(ushort4*)(x16 + (size_t)i*4) = o;
    }
}

__global__ __launch_bounds__(256) void count_kernel(
    const int* __restrict__ dst, int E, int* __restrict__ cnt)
{
    for (int e = blockIdx.x*blockDim.x + threadIdx.x; e < E; e += gridDim.x*blockDim.x)
        atomicAdd(&cnt[dst[e]], 1);
}

__global__ __launch_bounds__(1024) void scan_kernel(
    const int* __restrict__ cnt, int n, int E,
    int* __restrict__ offs, int* __restrict__ cursor)
{
    __shared__ int sh[1024];
    const int t = threadIdx.x;
    const int chunk = (n + 1023) >> 10;
    const int lo = t * chunk;
    const int hi = min(n, lo + chunk);
    int s = 0;
    for (int i = lo; i < hi; ++i) s += cnt[i];
    sh[t] = s;
    __syncthreads();
    for (int d = 1; d < 1024; d <<= 1) {
        int v = (t >= d) ? sh[t - d] : 0;
        __syncthreads();
        sh[t] += v;
        __syncthreads();
    }
    int base = sh[t] - s;
    for (int i = lo; i < hi; ++i) { int c = cnt[i]; offs[i] = base; cursor[i] = base; base += c; }
    if (t == 1023) offs[n] = E;
}

// CSR scatter + f16 conversion of edge_attr into permuted order (sequential
// reads per wave later). edsrc[p] = src row index.
__global__ __launch_bounds__(256) void scatter_kernel(
    const int* __restrict__ src, const int* __restrict__ dst,
    const float* __restrict__ attr, int E,
    int* __restrict__ cursor, int* __restrict__ edsrc, uint4* __restrict__ attrp)
{
    for (int e = blockIdx.x*blockDim.x + threadIdx.x; e < E; e += gridDim.x*blockDim.x) {
        int p = atomicAdd(&cursor[dst[e]], 1);
        edsrc[p] = src[e];
        const float4* ar = (const float4*)(attr + (size_t)e*16);
        float4 v0 = ar[0], v1 = ar[1], v2 = ar[2], v3 = ar[3];
        uint4 o0, o1;
        o0.x = pkh(v0.x, v0.y); o0.y = pkh(v0.z, v0.w);
        o0.z = pkh(v1.x, v1.y); o0.w = pkh(v1.z, v1.w);
        o1.x = pkh(v2.x, v2.y); o1.y = pkh(v2.z, v2.w);
        o1.z = pkh(v3.x, v3.y); o1.w = pkh(v3.z, v3.w);
        attrp[2*(size_t)p] = o0; attrp[2*(size_t)p + 1] = o1;
    }
}

__global__ __launch_bounds__(256) void goff_kernel(
    const int* __restrict__ batch, int n, int* __restrict__ goff)
{
    int g = blockIdx.x*blockDim.x + threadIdx.x;
    if (g > NGRAPH) return;
    if (g == NGRAPH) { goff[NGRAPH] = n; return; }
    int lo = 0, hi = n;
    while (lo < hi) { int m = (lo + hi) >> 1; if (batch[m] < g) lo = m + 1; else hi = m; }
    goff[g] = lo;
}

// ---------------------------------------------------------------------------
// bf16 MFMA GEMM: out16[r][c] = bf16( relu((X16[r]@W)[c]*sc+of) + resid )
// Block: 4 waves x 16 rows = 64 rows. W (pre-transposed Wt[n][k]) staged in
// LDS with XOR swizzle (T2) to kill the 16-way ds_read_b128 conflict.
// mfma_f32_16x16x32_bf16: A lane m=l&15,k=(l>>4)*8+j; B lane n=l&15, same k;
// D lane col=l&15, row=(l>>4)*4+r  [m89-verified].
// ---------------------------------------------------------------------------
__global__ __launch_bounds__(256) void conv_mfma_kernel(
    const unsigned short* __restrict__ X16, int M,
    const unsigned short* __restrict__ Wt,
    const float* __restrict__ scale, const float* __restrict__ off,
    const unsigned short* __restrict__ resid16,
    unsigned short* __restrict__ out16, int do_relu)
{
    __shared__ unsigned short Ws[128*128];
    for (int i = threadIdx.x*8; i < 128*128; i += 256*8) {
        int row = i >> 7;
        int bo = (i & 127) * 2;
        int4 v = *(const int4*)(Wt + i);
        *(int4*)((char*)Ws + row*256 + (bo ^ ((row & 7) << 4))) = v;
    }
    __syncthreads();
    const int wave = threadIdx.x >> 6, lane = threadIdx.x & 63;
    const int row0 = blockIdx.x*64 + wave*16;
    const int l15 = lane & 15, l4 = lane >> 4;
    int arow = row0 + l15; if (arow > M-1) arow = M-1;
    const unsigned short* ap = X16 + (size_t)arow*128 + l4*8;
    f32x4 acc[8];
    #pragma unroll
    for (int t = 0; t < 8; ++t) acc[t] = f32x4{0.f, 0.f, 0.f, 0.f};
    #pragma unroll
    for (int ks = 0; ks < 4; ++ks) {
        bf16x8 a = *(const bf16x8*)(ap + ks*32);
        #pragma unroll
        for (int t = 0; t < 8; ++t) {
            int brow = t*16 + l15;
            int bo = ks*64 + l4*16;
            bf16x8 b = *(const bf16x8*)((const char*)Ws + brow*256 + (bo ^ ((brow & 7) << 4)));
            acc[t] = __builtin_amdgcn_mfma_f32_16x16x32_bf16(a, b, acc[t], 0, 0, 0);
        }
    }
    #pragma unroll
    for (int t = 0; t < 8; ++t) {
        int col = t*16 + l15;
        float sc = scale[col], of = off[col];
        #pragma unroll
        for (int r = 0; r < 4; ++r) {
            int row = row0 + l4*4 + r;
            if (row < M) {
                float y = fmaf(acc[t][r], sc, of);
                if (do_relu) y = fmaxf(y, 0.f);
                if (resid16) y += uif((u32)resid16[(size_t)row*128 + col] << 16);
                out16[(size_t)row*128 + col] = bf16r(y);
            }
        }
    }
}

// ---------------------------------------------------------------------------
// agg: one wave per dst node, 2 channels/lane. Sequential attrp stream,
// bf16 h gather (1 dword/lane), f16 dot2 edge-MLP, explicit 2-deep pipeline
// with static register rotation. Epilogue writes C16 = bf16((1+eps)h + acc).
// ---------------------------------------------------------------------------
__device__ __forceinline__ void edge_compute(
    const u32* wA, const u32* wB, uint4 a0, uint4 a1, u32 h,
    float sc0, float sc1, float of0, float of1, float& acc0, float& acc1)
{
    u32 av[8] = {a0.x, a0.y, a0.z, a0.w, a1.x, a1.y, a1.z, a1.w};
    float r0 = 0.f, r1 = 0.f;
    #pragma unroll
    for (int kk = 0; kk < 8; ++kk) {
        r0 = fdot2w(av[kk], wA[kk], r0);
        r1 = fdot2w(av[kk], wB[kk], r1);
    }
    float ea0 = fmaxf(fmaf(r0, sc0, of0), 0.f);
    float ea1 = fmaxf(fmaf(r1, sc1, of1), 0.f);
    acc0 += fmaxf(uif(h << 16) + ea0, 0.f);
    acc1 += fmaxf(uif(h & 0xFFFF0000u) + ea1, 0.f);
}

__global__ __launch_bounds__(256) void agg_kernel(
    const u32* __restrict__ h16, const uint4* __restrict__ attrp,
    const int* __restrict__ edsrc, const int* __restrict__ offs,
    const u32* __restrict__ wpk,
    const float* __restrict__ escale, const float* __restrict__ eoff,
    const float* __restrict__ epsp, int layer,
    u32* __restrict__ C16, int n)
{
    const int wave = threadIdx.x >> 6, lane = threadIdx.x & 63;
    const int c0 = lane * 2;
    u32 wA[8], wB[8];
    #pragma unroll
    for (int kk = 0; kk < 8; ++kk) {
        wA[kk] = wpk[(layer*8 + kk)*128 + c0];
        wB[kk] = wpk[(layer*8 + kk)*128 + c0 + 1];
    }
    const float sc0 = escale[c0], sc1 = escale[c0+1];
    const float of0 = eoff[c0],   of1 = eoff[c0+1];
    const float epsv = 1.0f + epsp[layer];
    for (int node = blockIdx.x*4 + wave; node < n; node += gridDim.x*4) {
        const int beg = offs[node], end = offs[node+1];
        float acc0 = 0.f, acc1 = 0.f;
        if (beg < end) {
            int i = beg;
            uint4 aA0 = attrp[2*(size_t)i], aA1 = attrp[2*(size_t)i + 1];
            u32 hA = h16[(size_t)edsrc[i]*64 + lane];
            int sN = edsrc[(i+1 < end) ? i+1 : i];
            for (++i; i < end; ++i) {
                uint4 aB0 = attrp[2*(size_t)i], aB1 = attrp[2*(size_t)i + 1];
                u32 hB = h16[(size_t)sN*64 + lane];
                int sNN = edsrc[(i+1 < end) ? i+1 : i];
                edge_compute(wA, wB, aA0, aA1, hA, sc0, sc1, of0, of1, acc0, acc1);
                aA0 = aB0; aA1 = aB1; hA = hB; sN = sNN;
            }
            edge_compute(wA, wB, aA0, aA1, hA, sc0, sc1, of0, of1, acc0, acc1);
        }
        u32 hn = h16[(size_t)node*64 + lane];
        float t0 = fmaf(epsv, uif(hn << 16), acc0);
        float t1 = fmaf(epsv, uif(hn & 0xFFFF0000u), acc1);
        C16[(size_t)node*64 + lane] = pack_bf16(t0, t1);
    }
}

__global__ __launch_bounds__(256) void pool_kernel(
    const u32* __restrict__ h16, const int* __restrict__ goff,
    float* __restrict__ pooled)
{
    const int wave = threadIdx.x >> 6, lane = threadIdx.x & 63;
    const int g = blockIdx.x*4 + wave;
    if (g >= NGRAPH) return;
    float ax = 0.f, ay = 0.f;
    const int beg = goff[g], end = goff[g+1];
    for (int node = beg; node < end; ++node) {
        u32 v = h16[(size_t)node*64 + lane];
        ax += uif(v << 16); ay += uif(v & 0xFFFF0000u);
    }
    *(float2*)&pooled[g*128 + lane*2] = make_float2(ax, ay);
}

// fp32 vector GEMM for the small output MLP (512 rows)
__global__ __launch_bounds__(256) void gemm128_kernel(
    const float* __restrict__ in, int rows,
    const float* __restrict__ W,
    const float* __restrict__ scale, const float* __restrict__ off,
    float* out, int do_relu)
{
    __shared__ float Wsh[128*128];
    for (int i = threadIdx.x*4; i < 128*128; i += 256*4)
        *(float4*)&Wsh[i] = *(const float4*)&W[i];
    __syncthreads();
    const int wave = threadIdx.x >> 6, lane = threadIdx.x & 63;
    const int c0 = lane * 2;
    const float sc0 = scale ? scale[c0]   : 1.0f;
    const float sc1 = scale ? scale[c0+1] : 1.0f;
    const float of0 = off ? off[c0]   : 0.0f;
    const float of1 = off ? off[c0+1] : 0.0f;
    for (int rp = blockIdx.x*4 + wave; rp*2 < rows; rp += gridDim.x*4) {
        const int row0 = __builtin_amdgcn_readfirstlane(rp * 2);
        const float* xr = in + (size_t)row0 * 128;
        float a00 = 0.f, a01 = 0.f, a10 = 0.f, a11 = 0.f;
        #pragma unroll 8
        for (int k = 0; k < 128; ++k) {
            float x0 = xr[k];
            float x1 = xr[128 + k];
            float2 w = *(const float2*)&Wsh[k*128 + c0];
            a00 = fmaf(x0, w.x, a00); a01 = fmaf(x0, w.y, a01);
            a10 = fmaf(x1, w.x, a10); a11 = fmaf(x1, w.y, a11);
        }
        float y00 = fmaf(a00, sc0, of0), y01 = fmaf(a01, sc1, of1);
        float y10 = fmaf(a10, sc0, of0), y11 = fmaf(a11, sc1, of1);
        if (do_relu) {
            y00 = fmaxf(y00, 0.f); y01 = fmaxf(y01, 0.f);
            y10 = fmaxf(y10, 0.f); y11 = fmaxf(y11, 0.f);
        }
        *(float2*)&out[(size_t)row0*128 + c0]     = make_float2(y00, y01);
        *(float2*)&out[(size_t)(row0+1)*128 + c0] = make_float2(y10, y11);
    }
}

extern "C" void kernel_launch(void* const* d_in, const int* in_sizes, int n_in,
                              void* d_out, int out_size, void* d_ws, size_t ws_size,
                              hipStream_t stream)
{
    const float* x         = (const float*)d_in[0];
    const int*   eidx      = (const int*)d_in[1];
    const float* eattr     = (const float*)d_in[2];
    const int*   batch     = (const int*)d_in[3];
    const float* in_W      = (const float*)d_in[4];
    const float* in_b      = (const float*)d_in[5];
    const float* in_g      = (const float*)d_in[6];
    const float* in_beta   = (const float*)d_in[7];
    const float* edge_W    = (const float*)d_in[8];
    const float* edge_b    = (const float*)d_in[9];
    const float* edge_g    = (const float*)d_in[10];
    const float* edge_beta = (const float*)d_in[11];
    const float* conv_W    = (const float*)d_in[12];
    const float* epsp      = (const float*)d_in[13];
    const float* bn_g      = (const float*)d_in[14];
    const float* bn_b      = (const float*)d_in[15];
    const float* out_W1    = (const float*)d_in[16];
    const float* out_b1    = (const float*)d_in[17];
    const float* out_g1    = (const float*)d_in[18];
    const float* out_beta1 = (const float*)d_in[19];
    const float* out_W2    = (const float*)d_in[20];
    const float* out_b2    = (const float*)d_in[21];

    const int N = in_sizes[0] / 128;
    const int E = in_sizes[1] / 2;
    const int* src = eidx;
    const int* dst = eidx + E;

    char* ws = (char*)d_ws;
    size_t o = 0;
    auto alloc = [&](size_t bytes) { void* p = ws + o; o = (o + bytes + 255) & ~(size_t)255; return p; };
    unsigned short* h16a = (unsigned short*)alloc((size_t)N * 128 * 2);
    unsigned short* h16b = (unsigned short*)alloc((size_t)N * 128 * 2);
    unsigned short* C16  = (unsigned short*)alloc((size_t)N * 128 * 2);  // also x16
    uint4* attrp         = (uint4*)alloc((size_t)E * 32);
    int*   edsrc         = (int*)alloc((size_t)E * 4);
    int*   offs          = (int*)alloc((size_t)(N + 1) * 4);
    int*   cursor        = (int*)alloc((size_t)N * 4);
    int*   cnt           = (int*)alloc((size_t)N * 4);
    int*   goff          = (int*)alloc((NGRAPH + 1) * 4);
    float* pooled        = (float*)alloc(NGRAPH * 128 * 4);
    float* o1            = (float*)alloc(NGRAPH * 128 * 4);
    float* consts        = (float*)alloc(2560 * 4);
    u32*   wpk           = (u32*)alloc(4 * 8 * 128 * 4);
    unsigned short* WtAll = (unsigned short*)alloc(5 * 128 * 128 * 2);

    prep_kernel<<<1, 256, 0, stream>>>(in_b, in_g, in_beta, edge_W,
                                       edge_b, edge_g, edge_beta,
                                       bn_g, bn_b, out_b1, out_g1, out_beta1,
                                       consts, wpk);
    prepw_kernel<<<80, 256, 0, stream>>>(in_W, conv_W, WtAll);
    xconv_kernel<<<2048, 256, 0, stream>>>(x, C16, N * 32);

    hipMemsetAsync(cnt, 0, (size_t)N * 4, stream);
    count_kernel<<<2048, 256, 0, stream>>>(dst, E, cnt);
    scan_kernel<<<1, 1024, 0, stream>>>(cnt, N, E, offs, cursor);
    scatter_kernel<<<2048, 256, 0, stream>>>(src, dst, eattr, E, cursor, edsrc, attrp);
    goff_kernel<<<3, 256, 0, stream>>>(batch, N, goff);

    const int gblocks = (N + 63) / 64;
    // input encoder: h16a = bf16(relu(bn(x@in_W + b)))
    conv_mfma_kernel<<<gblocks, 256, 0, stream>>>(C16, N, WtAll,
                                                  consts, consts + 128,
                                                  nullptr, h16a, 1);

    unsigned short* cur = h16a;
    unsigned short* nxt = h16b;
    for (int l = 0; l < 4; ++l) {
        agg_kernel<<<2048, 256, 0, stream>>>((const u32*)cur, attrp, edsrc, offs,
                                             wpk,
                                             consts + 256 + l*128,
                                             consts + 768 + l*128,
                                             epsp, l, (u32*)C16, N);
        conv_mfma_kernel<<<gblocks, 256, 0, stream>>>(C16, N,
                                                      WtAll + (size_t)(1 + l)*16384,
                                                      consts + 1280 + l*128,
                                                      consts + 1792 + l*128,
                                                      cur, nxt, 1);
        unsigned short* t = cur; cur = nxt; nxt = t;
    }

    pool_kernel<<<128, 256, 0, stream>>>((const u32*)cur, goff, pooled);

    gemm128_kernel<<<64, 256, 0, stream>>>(pooled, NGRAPH, out_W1,
                                           consts + 2304, consts + 2432, o1, 1);
    gemm128_kernel<<<64, 256, 0, stream>>>(o1, NGRAPH, out_W2,
                                           nullptr, out_b2, (float*)d_out, 0);
}

// Round 6
// 937.796 us; speedup vs baseline: 3.2958x; 1.0644x over previous
//
#include <hip/hip_runtime.h>
#include <stdint.h>

typedef uint32_t u32;
typedef _Float16 h2v __attribute__((ext_vector_type(2)));
typedef __attribute__((ext_vector_type(8))) short bf16x8;
typedef __attribute__((ext_vector_type(4))) float f32x4;

#define NGRAPH 512

__device__ __forceinline__ float uif(u32 u) { return __builtin_bit_cast(float, u); }
__device__ __forceinline__ u32 fiu(float f) { return __builtin_bit_cast(u32, f); }
__device__ __forceinline__ unsigned short bf16r(float f) {
    return (unsigned short)((fiu(f) + 0x8000u) >> 16);
}
__device__ __forceinline__ u32 pack_bf16(float lo, float hi) {
    return ((fiu(lo) + 0x8000u) >> 16) | ((fiu(hi) + 0x8000u) & 0xFFFF0000u);
}
__device__ __forceinline__ u32 pkh(float a, float b) {
    unsigned short la = __builtin_bit_cast(unsigned short, (_Float16)a);
    unsigned short hb = __builtin_bit_cast(unsigned short, (_Float16)b);
    return (u32)la | ((u32)hb << 16);
}
// v_dot2_f32_f16: c += a.lo*b.lo + a.hi*b.hi  (f32 accumulate — keeps range)
__device__ __forceinline__ float fdot2w(u32 a, u32 b, float c) {
#if __has_builtin(__builtin_amdgcn_fdot2)
    return __builtin_amdgcn_fdot2(__builtin_bit_cast(h2v, a),
                                  __builtin_bit_cast(h2v, b), c, false);
#else
    h2v av = __builtin_bit_cast(h2v, a), bv = __builtin_bit_cast(h2v, b);
    return c + (float)av[0]*(float)bv[0] + (float)av[1]*(float)bv[1];
#endif
}

// ---------------------------------------------------------------------------
// prep: BN folding. consts layout:
// [0]enc_s [128]enc_o [256+l*128]edge_s [768+l*128]edge_o
// [1280+l*128]conv_s [1792+l*128]conv_o [2304]out1_s [2432]out1_o
// wpk[(l*8+kk)*128+c] = f16pair(W[2kk][c], W[2kk+1][c])
// ---------------------------------------------------------------------------
__global__ __launch_bounds__(256) void prep_kernel(
    const float* __restrict__ in_b, const float* __restrict__ in_g, const float* __restrict__ in_beta,
    const float* __restrict__ edge_W,
    const float* __restrict__ edge_b, const float* __restrict__ edge_g, const float* __restrict__ edge_beta,
    const float* __restrict__ bn_g, const float* __restrict__ bn_b,
    const float* __restrict__ out_b1, const float* __restrict__ out_g1, const float* __restrict__ out_beta1,
    float* __restrict__ consts, u32* __restrict__ wpk)
{
    int c = threadIdx.x;
    if (c >= 128) return;
    const float rs = rsqrtf(1.0f + 1e-5f);
    float es = in_g[c] * rs;
    consts[c]       = es;
    consts[128 + c] = in_b[c] * es + in_beta[c];
    for (int l = 0; l < 4; ++l) {
        float s = edge_g[l*128 + c] * rs;
        consts[256  + l*128 + c] = s;
        consts[768  + l*128 + c] = edge_b[l*128 + c] * s + edge_beta[l*128 + c];
        float bs = bn_g[l*128 + c] * rs;
        consts[1280 + l*128 + c] = bs;
        consts[1792 + l*128 + c] = bn_b[l*128 + c];
        for (int kk = 0; kk < 8; ++kk) {
            float w0 = edge_W[(l*16 + 2*kk)*128 + c];
            float w1 = edge_W[(l*16 + 2*kk + 1)*128 + c];
            wpk[(l*8 + kk)*128 + c] = pkh(w0, w1);
        }
    }
    float s1 = out_g1[c] * rs;
    consts[2304 + c] = s1;
    consts[2432 + c] = out_b1[c] * s1 + out_beta1[c];
}

// Wt[w][n][k] = bf16(W[w][k][n]); w=0 encoder, w=1..4 conv layers
__global__ __launch_bounds__(256) void prepw_kernel(
    const float* __restrict__ in_W, const float* __restrict__ conv_W,
    unsigned short* __restrict__ WtAll)
{
    for (int idx = blockIdx.x*blockDim.x + threadIdx.x; idx < 5*128*128;
         idx += gridDim.x*blockDim.x) {
        int w = idx >> 14, rem = idx & 16383;
        int nn = rem >> 7, kk = rem & 127;
        const float* S = (w == 0) ? in_W : conv_W + (size_t)(w-1)*16384;
        WtAll[idx] = bf16r(S[kk*128 + nn]);
    }
}

// f32 x -> bf16 pairs
__global__ __launch_bounds__(256) void xconv_kernel(
    const float* __restrict__ x, u32* __restrict__ x16, int n4)
{
    for (int i = blockIdx.x*blockDim.x + threadIdx.x; i < n4;
         i += gridDim.x*blockDim.x) {
        float4 v = *(const float4*)(x + (size_t)i*4);
        uint2 o; o.x = pack_bf16(v.x, v.y); o.y = pack_bf16(v.z, v.w);
        *(uint2*)(x16 + (size_t)i*2) = o;
    }
}

__global__ __launch_bounds__(256) void count_kernel(
    const int* __restrict__ dst, int E, int* __restrict__ cnt)
{
    for (int e = blockIdx.x*blockDim.x + threadIdx.x; e < E; e += gridDim.x*blockDim.x)
        atomicAdd(&cnt[dst[e]], 1);
}

__global__ __launch_bounds__(1024) void scan_kernel(
    const int* __restrict__ cnt, int n, int E,
    int* __restrict__ offs, int* __restrict__ cursor)
{
    __shared__ int sh[1024];
    const int t = threadIdx.x;
    const int chunk = (n + 1023) >> 10;
    const int lo = t * chunk;
    const int hi = min(n, lo + chunk);
    int s = 0;
    for (int i = lo; i < hi; ++i) s += cnt[i];
    sh[t] = s;
    __syncthreads();
    for (int d = 1; d < 1024; d <<= 1) {
        int v = (t >= d) ? sh[t - d] : 0;
        __syncthreads();
        sh[t] += v;
        __syncthreads();
    }
    int base = sh[t] - s;
    for (int i = lo; i < hi; ++i) { int c = cnt[i]; offs[i] = base; cursor[i] = base; base += c; }
    if (t == 1023) offs[n] = E;
}

// CSR scatter: attrp[p] = 8 dwords of packed f16 pairs (32B/edge);
// srcoff[p] = src row byte offset (src*256).
__global__ __launch_bounds__(256) void scatter_kernel(
    const int* __restrict__ src, const int* __restrict__ dst,
    const float* __restrict__ attr, int E,
    int* __restrict__ cursor, int* __restrict__ srcoff, uint4* __restrict__ attrp)
{
    for (int e = blockIdx.x*blockDim.x + threadIdx.x; e < E; e += gridDim.x*blockDim.x) {
        int p = atomicAdd(&cursor[dst[e]], 1);
        srcoff[p] = src[e] * 256;
        const float4* ar = (const float4*)(attr + (size_t)e*16);
        float4 v0 = ar[0], v1 = ar[1], v2 = ar[2], v3 = ar[3];
        uint4 o0, o1;
        o0.x = pkh(v0.x, v0.y); o0.y = pkh(v0.z, v0.w);
        o0.z = pkh(v1.x, v1.y); o0.w = pkh(v1.z, v1.w);
        o1.x = pkh(v2.x, v2.y); o1.y = pkh(v2.z, v2.w);
        o1.z = pkh(v3.x, v3.y); o1.w = pkh(v3.z, v3.w);
        attrp[2*(size_t)p] = o0; attrp[2*(size_t)p + 1] = o1;
    }
}

__global__ __launch_bounds__(256) void goff_kernel(
    const int* __restrict__ batch, int n, int* __restrict__ goff)
{
    int g = blockIdx.x*blockDim.x + threadIdx.x;
    if (g > NGRAPH) return;
    if (g == NGRAPH) { goff[NGRAPH] = n; return; }
    int lo = 0, hi = n;
    while (lo < hi) { int m = (lo + hi) >> 1; if (batch[m] < g) lo = m + 1; else hi = m; }
    goff[g] = lo;
}

// ---------------------------------------------------------------------------
// bf16 MFMA GEMM, in-place safe (out may alias X: each wave reads only its
// own 16 rows before storing them; clamped tail reads touch only rows whose
// writes are predicated off). out = bf16(relu((X@W)*sc+of) + resid)
// ---------------------------------------------------------------------------
__global__ __launch_bounds__(256) void conv_mfma_kernel(
    const unsigned short* X16, int M,
    const unsigned short* __restrict__ Wt,
    const float* __restrict__ scale, const float* __restrict__ off,
    const unsigned short* __restrict__ resid16,
    unsigned short* out16, int do_relu)
{
    __shared__ unsigned short Ws[128*128];
    for (int i = threadIdx.x*8; i < 128*128; i += 256*8) {
        int row = i >> 7;
        int bo = (i & 127) * 2;
        int4 v = *(const int4*)(Wt + i);
        *(int4*)((char*)Ws + row*256 + (bo ^ ((row & 7) << 4))) = v;
    }
    __syncthreads();
    const int wave = threadIdx.x >> 6, lane = threadIdx.x & 63;
    const int row0 = blockIdx.x*64 + wave*16;
    const int l15 = lane & 15, l4 = lane >> 4;
    int arow = row0 + l15; if (arow > M-1) arow = M-1;
    const unsigned short* ap = X16 + (size_t)arow*128 + l4*8;
    f32x4 acc[8];
    #pragma unroll
    for (int t = 0; t < 8; ++t) acc[t] = f32x4{0.f, 0.f, 0.f, 0.f};
    #pragma unroll
    for (int ks = 0; ks < 4; ++ks) {
        bf16x8 a = *(const bf16x8*)(ap + ks*32);
        #pragma unroll
        for (int t = 0; t < 8; ++t) {
            int brow = t*16 + l15;
            int bo = ks*64 + l4*16;
            bf16x8 b = *(const bf16x8*)((const char*)Ws + brow*256 + (bo ^ ((brow & 7) << 4)));
            acc[t] = __builtin_amdgcn_mfma_f32_16x16x32_bf16(a, b, acc[t], 0, 0, 0);
        }
    }
    #pragma unroll
    for (int t = 0; t < 8; ++t) {
        int col = t*16 + l15;
        float sc = scale[col], of = off[col];
        #pragma unroll
        for (int r = 0; r < 4; ++r) {
            int row = row0 + l4*4 + r;
            if (row < M) {
                float y = fmaf(acc[t][r], sc, of);
                if (do_relu) y = fmaxf(y, 0.f);
                if (resid16) y += uif((u32)resid16[(size_t)row*128 + col] << 16);
                out16[(size_t)row*128 + col] = bf16r(y);
            }
        }
    }
}

// ---------------------------------------------------------------------------
// agg: one wave per dst node, 2 channels/lane. Edge stream (attrp, srcoff) is
// wave-uniform -> readfirstlane -> scalar loads. MLP = 16 v_dot2_f32_f16
// (f32 accum). h in bf16, epilogue f32 (range-safe: |h| can reach ~7e5).
// ---------------------------------------------------------------------------
__global__ __launch_bounds__(256) void agg_kernel(
    const char* __restrict__ hb,          // bf16 h, row = 256 bytes
    const uint4* __restrict__ attrp,
    const int* __restrict__ srcoff,
    const int* __restrict__ offs,
    const u32* __restrict__ wpk,
    const float* __restrict__ escale, const float* __restrict__ eoff,
    const float* __restrict__ epsp, int layer,
    u32* __restrict__ C16, int n)
{
    const int wave = threadIdx.x >> 6, lane = threadIdx.x & 63;
    const int lane4 = lane * 4;
    const int c0 = lane * 2;
    u32 wA[8], wB[8];
    #pragma unroll
    for (int kk = 0; kk < 8; ++kk) {
        wA[kk] = wpk[(layer*8 + kk)*128 + c0];
        wB[kk] = wpk[(layer*8 + kk)*128 + c0 + 1];
    }
    const float sc0 = escale[c0], sc1 = escale[c0+1];
    const float of0 = eoff[c0],   of1 = eoff[c0+1];
    const float epsv = 1.0f + epsp[layer];

    for (int node = blockIdx.x*4 + wave; node < n; node += gridDim.x*4) {
        const int beg = offs[node], end = offs[node+1];
        float acc0 = 0.f, acc1 = 0.f;

        auto edge = [&](int idx) {
            const int iu = __builtin_amdgcn_readfirstlane(idx);
            const uint4 q0 = attrp[2*(size_t)iu];
            const uint4 q1 = attrp[2*(size_t)iu + 1];
            const int so = srcoff[iu];
            const u32 hv = *(const u32*)(hb + so + lane4);
            float r0 = 0.f, r1 = 0.f;
            r0 = fdot2w(q0.x, wA[0], r0); r1 = fdot2w(q0.x, wB[0], r1);
            r0 = fdot2w(q0.y, wA[1], r0); r1 = fdot2w(q0.y, wB[1], r1);
            r0 = fdot2w(q0.z, wA[2], r0); r1 = fdot2w(q0.z, wB[2], r1);
            r0 = fdot2w(q0.w, wA[3], r0); r1 = fdot2w(q0.w, wB[3], r1);
            r0 = fdot2w(q1.x, wA[4], r0); r1 = fdot2w(q1.x, wB[4], r1);
            r0 = fdot2w(q1.y, wA[5], r0); r1 = fdot2w(q1.y, wB[5], r1);
            r0 = fdot2w(q1.z, wA[6], r0); r1 = fdot2w(q1.z, wB[6], r1);
            r0 = fdot2w(q1.w, wA[7], r0); r1 = fdot2w(q1.w, wB[7], r1);
            float ea0 = fmaxf(fmaf(r0, sc0, of0), 0.f);
            float ea1 = fmaxf(fmaf(r1, sc1, of1), 0.f);
            float h0 = uif(hv << 16);
            float h1 = uif(hv & 0xFFFF0000u);
            acc0 += fmaxf(h0 + ea0, 0.f);
            acc1 += fmaxf(h1 + ea1, 0.f);
        };

        int i = beg;
        for (; i + 1 < end; i += 2) { edge(i); edge(i + 1); }
        if (i < end) edge(i);

        const u32 hn = *(const u32*)(hb + (size_t)node*256 + lane4);
        float t0 = fmaf(epsv, uif(hn << 16), acc0);
        float t1 = fmaf(epsv, uif(hn & 0xFFFF0000u), acc1);
        C16[(size_t)node*64 + lane] = pack_bf16(t0, t1);
    }
}

__global__ __launch_bounds__(256) void pool_kernel(
    const u32* __restrict__ h16, const int* __restrict__ goff,
    float* __restrict__ pooled)
{
    const int wave = threadIdx.x >> 6, lane = threadIdx.x & 63;
    const int g = blockIdx.x*4 + wave;
    if (g >= NGRAPH) return;
    float ax = 0.f, ay = 0.f;
    const int beg = goff[g], end = goff[g+1];
    for (int node = beg; node < end; ++node) {
        u32 v = h16[(size_t)node*64 + lane];
        ax += uif(v << 16); ay += uif(v & 0xFFFF0000u);
    }
    *(float2*)&pooled[g*128 + lane*2] = make_float2(ax, ay);
}

// fp32 vector GEMM for the small output MLP (512 rows)
__global__ __launch_bounds__(256) void gemm128_kernel(
    const float* __restrict__ in, int rows,
    const float* __restrict__ W,
    const float* __restrict__ scale, const float* __restrict__ off,
    float* out, int do_relu)
{
    __shared__ float Wsh[128*128];
    for (int i = threadIdx.x*4; i < 128*128; i += 256*4)
        *(float4*)&Wsh[i] = *(const float4*)&W[i];
    __syncthreads();
    const int wave = threadIdx.x >> 6, lane = threadIdx.x & 63;
    const int c0 = lane * 2;
    const float sc0 = scale ? scale[c0]   : 1.0f;
    const float sc1 = scale ? scale[c0+1] : 1.0f;
    const float of0 = off ? off[c0]   : 0.0f;
    const float of1 = off ? off[c0+1] : 0.0f;
    for (int rp = blockIdx.x*4 + wave; rp*2 < rows; rp += gridDim.x*4) {
        const int row0 = __builtin_amdgcn_readfirstlane(rp * 2);
        const float* xr = in + (size_t)row0 * 128;
        float a00 = 0.f, a01 = 0.f, a10 = 0.f, a11 = 0.f;
        #pragma unroll 8
        for (int k = 0; k < 128; ++k) {
            float x0 = xr[k];
            float x1 = xr[128 + k];
            float2 w = *(const float2*)&Wsh[k*128 + c0];
            a00 = fmaf(x0, w.x, a00); a01 = fmaf(x0, w.y, a01);
            a10 = fmaf(x1, w.x, a10); a11 = fmaf(x1, w.y, a11);
        }
        float y00 = fmaf(a00, sc0, of0), y01 = fmaf(a01, sc1, of1);
        float y10 = fmaf(a10, sc0, of0), y11 = fmaf(a11, sc1, of1);
        if (do_relu) {
            y00 = fmaxf(y00, 0.f); y01 = fmaxf(y01, 0.f);
            y10 = fmaxf(y10, 0.f); y11 = fmaxf(y11, 0.f);
        }
        *(float2*)&out[(size_t)row0*128 + c0]     = make_float2(y00, y01);
        *(float2*)&out[(size_t)(row0+1)*128 + c0] = make_float2(y10, y11);
    }
}

extern "C" void kernel_launch(void* const* d_in, const int* in_sizes, int n_in,
                              void* d_out, int out_size, void* d_ws, size_t ws_size,
                              hipStream_t stream)
{
    const float* x         = (const float*)d_in[0];
    const int*   eidx      = (const int*)d_in[1];
    const float* eattr     = (const float*)d_in[2];
    const int*   batch     = (const int*)d_in[3];
    const float* in_W      = (const float*)d_in[4];
    const float* in_b      = (const float*)d_in[5];
    const float* in_g      = (const float*)d_in[6];
    const float* in_beta   = (const float*)d_in[7];
    const float* edge_W    = (const float*)d_in[8];
    const float* edge_b    = (const float*)d_in[9];
    const float* edge_g    = (const float*)d_in[10];
    const float* edge_beta = (const float*)d_in[11];
    const float* conv_W    = (const float*)d_in[12];
    const float* epsp      = (const float*)d_in[13];
    const float* bn_g      = (const float*)d_in[14];
    const float* bn_b      = (const float*)d_in[15];
    const float* out_W1    = (const float*)d_in[16];
    const float* out_b1    = (const float*)d_in[17];
    const float* out_g1    = (const float*)d_in[18];
    const float* out_beta1 = (const float*)d_in[19];
    const float* out_W2    = (const float*)d_in[20];
    const float* out_b2    = (const float*)d_in[21];

    const int N = in_sizes[0] / 128;
    const int E = in_sizes[1] / 2;
    const int* src = eidx;
    const int* dst = eidx + E;

    char* ws = (char*)d_ws;
    size_t o = 0;
    auto alloc = [&](size_t bytes) { void* p = ws + o; o = (o + bytes + 255) & ~(size_t)255; return p; };
    unsigned short* P    = (unsigned short*)alloc((size_t)N * 128 * 2);
    unsigned short* Q    = (unsigned short*)alloc((size_t)N * 128 * 2);
    uint4* attrp         = (uint4*)alloc((size_t)E * 32);
    int*   srcoff        = (int*)alloc((size_t)E * 4);
    int*   offs          = (int*)alloc((size_t)(N + 1) * 4);
    int*   cursor        = (int*)alloc((size_t)N * 4);
    int*   cnt           = (int*)alloc((size_t)N * 4);
    int*   goff          = (int*)alloc((NGRAPH + 1) * 4);
    float* pooled        = (float*)alloc(NGRAPH * 128 * 4);
    float* o1            = (float*)alloc(NGRAPH * 128 * 4);
    float* consts        = (float*)alloc(2560 * 4);
    u32*   wpk           = (u32*)alloc(4 * 8 * 128 * 4);
    unsigned short* WtAll = (unsigned short*)alloc(5 * 128 * 128 * 2);

    prep_kernel<<<1, 256, 0, stream>>>(in_b, in_g, in_beta, edge_W,
                                       edge_b, edge_g, edge_beta,
                                       bn_g, bn_b, out_b1, out_g1, out_beta1,
                                       consts, wpk);
    prepw_kernel<<<80, 256, 0, stream>>>(in_W, conv_W, WtAll);
    xconv_kernel<<<2048, 256, 0, stream>>>(x, (u32*)Q, N * 32);

    (void)hipMemsetAsync(cnt, 0, (size_t)N * 4, stream);
    count_kernel<<<2048, 256, 0, stream>>>(dst, E, cnt);
    scan_kernel<<<1, 1024, 0, stream>>>(cnt, N, E, offs, cursor);
    scatter_kernel<<<2048, 256, 0, stream>>>(src, dst, eattr, E, cursor, srcoff, attrp);
    goff_kernel<<<3, 256, 0, stream>>>(batch, N, goff);

    const int gblocks = (N + 63) / 64;
    // input encoder, in-place on Q: h0 = bf16(relu(bn(x@in_W)))
    conv_mfma_kernel<<<gblocks, 256, 0, stream>>>(Q, N, WtAll,
                                                  consts, consts + 128,
                                                  nullptr, Q, 1);

    unsigned short* cur = Q;
    unsigned short* oth = P;
    for (int l = 0; l < 4; ++l) {
        agg_kernel<<<2048, 256, 0, stream>>>((const char*)cur, attrp, srcoff, offs,
                                             wpk,
                                             consts + 256 + l*128,
                                             consts + 768 + l*128,
                                             epsp, l, (u32*)oth, N);
        // conv in-place on oth, residual from cur
        conv_mfma_kernel<<<gblocks, 256, 0, stream>>>(oth, N,
                                                      WtAll + (size_t)(1 + l)*16384,
                                                      consts + 1280 + l*128,
                                                      consts + 1792 + l*128,
                                                      cur, oth, 1);
        unsigned short* t = cur; cur = oth; oth = t;
    }

    pool_kernel<<<128, 256, 0, stream>>>((const u32*)cur, goff, pooled);

    gemm128_kernel<<<64, 256, 0, stream>>>(pooled, NGRAPH, out_W1,
                                           consts + 2304, consts + 2432, o1, 1);
    gemm128_kernel<<<64, 256, 0, stream>>>(o1, NGRAPH, out_W2,
                                           nullptr, out_b2, (float*)d_out, 0);
}